// Round 7
// baseline (373.016 us; speedup 1.0000x reference)
//
#include <hip/hip_runtime.h>

// Problem constants
#define KB_TOT 305        // 300 emb k-blocks (64 wide) + 5 c-blocks
#define KPAD   19520      // 305*64 reordered/padded K
#define BROW   39040      // bytes per B_ws row (KPAD * 2)

typedef __attribute__((ext_vector_type(8))) short bf16x8_t;
typedef __attribute__((ext_vector_type(4))) float f32x4_t;

typedef const __attribute__((address_space(1))) unsigned int GAS_u32;
typedef __attribute__((address_space(3))) unsigned int LAS_u32;

__device__ inline unsigned short f2bf(float x) {
    union { float f; unsigned u; } a; a.f = x;
    unsigned r = a.u + 0x7fffu + ((a.u >> 16) & 1u);   // RNE, finite inputs
    return (unsigned short)(r >> 16);
}
__device__ inline float bf2f(unsigned short h) {
    union { unsigned u; float f; } a; a.u = ((unsigned)h) << 16; return a.f;
}
__device__ inline unsigned long long pack4bf(float x, float y, float z, float w) {
    return (unsigned long long)f2bf(x) | ((unsigned long long)f2bf(y) << 16)
         | ((unsigned long long)f2bf(z) << 32) | ((unsigned long long)f2bf(w) << 48);
}

// ---------- merged prep: emb->bf16 | c->Ac | gat_W->WT | W_se->Bws ----------
__global__ __launch_bounds__(256) void prep_kernel(
    const float* __restrict__ emb, const float* __restrict__ l_c,
    const float* __restrict__ m_c, const float* __restrict__ t_c,
    const float* __restrict__ W_se, const float* __restrict__ gat_W,
    unsigned short* __restrict__ ebf, unsigned short* __restrict__ Ac,
    unsigned short* __restrict__ WT, unsigned short* __restrict__ Bws) {
    __shared__ float tl[64 * 68];
    int bid = blockIdx.x, tid = threadIdx.x;
    if (bid < 125) {                       // emb -> bf16 (128,000 elems)
        int i4 = (bid * 256 + tid) * 4;
        float4 v = *(const float4*)(emb + i4);
        *(unsigned long long*)(ebf + i4) = pack4bf(v.x, v.y, v.z, v.w);
    } else if (bid < 2685) {               // Ac[8192][320]
        int lin = (bid - 125) * 256 + tid;
        int row = lin / 80, c4 = (lin - row * 80) * 4;
        float vv[4];
        #pragma unroll
        for (int ii = 0; ii < 4; ++ii) {
            int t = c4 + ii;
            float x = 0.f;
            if (t < 300) {
                int m = t / 100, s = t - m * 100;
                const float* C = (m == 0) ? l_c : ((m == 1) ? m_c : t_c);
                x = C[row * 100 + s] * 0.01f;
            }
            vv[ii] = x;
        }
        *(unsigned long long*)(Ac + row * 320 + c4) = pack4bf(vv[0], vv[1], vv[2], vv[3]);
    } else if (bid < 2721) {               // gat_W transpose -> WT bf16
        int idx = bid - 2685;
        int k0 = (idx % 6) * 64, n0 = (idx / 6) * 64;
        int rr = tid >> 2, c16 = (tid & 3) * 16;
        #pragma unroll
        for (int ii = 0; ii < 4; ++ii)
            *(float4*)(tl + rr * 68 + c16 + ii * 4) =
                *(const float4*)(gat_W + (k0 + rr) * 384 + n0 + c16 + ii * 4);
        __syncthreads();
        int c = tid >> 2, r16 = (tid & 3) * 16;
        unsigned long long* dst8 = (unsigned long long*)(WT + (n0 + c) * 384 + k0 + r16);
        #pragma unroll
        for (int q = 0; q < 4; ++q) {
            int rb = r16 + q * 4;
            dst8[q] = pack4bf(tl[(rb + 0) * 68 + c], tl[(rb + 1) * 68 + c],
                              tl[(rb + 2) * 68 + c], tl[(rb + 3) * 68 + c]);
        }
    } else {                               // W_se reorder+transpose -> Bws
        int idx = bid - 2721;              // 0..1829
        int kb = idx % 305, h0 = (idx / 305) * 64;
        int rr = tid >> 2, c16 = (tid & 3) * 16;
        float4 v[4];
        if (kb < 300) {
            int m = kb / 100, s = kb - m * 100;
            const float* srcp = W_se + (s * 195 + m * 65 + rr) * 384 + h0 + c16;
            #pragma unroll
            for (int ii = 0; ii < 4; ++ii) v[ii] = *(const float4*)(srcp + ii * 4);
        } else {
            int t = (kb - 300) * 64 + rr;
            if (t < 300) {
                int m = t / 100, s = t - m * 100;
                const float* srcp = W_se + (s * 195 + m * 65 + 64) * 384 + h0 + c16;
                #pragma unroll
                for (int ii = 0; ii < 4; ++ii) v[ii] = *(const float4*)(srcp + ii * 4);
            } else {
                #pragma unroll
                for (int ii = 0; ii < 4; ++ii) v[ii] = make_float4(0.f, 0.f, 0.f, 0.f);
            }
        }
        #pragma unroll
        for (int ii = 0; ii < 4; ++ii) *(float4*)(tl + rr * 68 + c16 + ii * 4) = v[ii];
        __syncthreads();
        int c = tid >> 2, r16 = (tid & 3) * 16;
        unsigned long long* dst8 =
            (unsigned long long*)(Bws + (unsigned)(h0 + c) * KPAD + kb * 64 + r16);
        #pragma unroll
        for (int q = 0; q < 4; ++q) {
            int rb = r16 + q * 4;
            dst8[q] = pack4bf(tl[(rb + 0) * 68 + c], tl[(rb + 1) * 68 + c],
                              tl[(rb + 2) * 68 + c], tl[(rb + 3) * 68 + c]);
        }
    }
}

// ---------- big GEMM: split-K x6, kc0 -> f32 fusion area, kc1..5 -> bf16 partials ----------
__global__ __launch_bounds__(256) void gemm_fused_kernel(
    const int* __restrict__ l_e, const int* __restrict__ m_e, const int* __restrict__ t_e,
    const unsigned short* __restrict__ emb_bf, const unsigned short* __restrict__ Ac_bf,
    const unsigned short* __restrict__ Bws, float* __restrict__ fusion_d,
    unsigned short* __restrict__ Pbf) {

    __shared__ alignas(16) unsigned short Al[128 * 64];
    __shared__ alignas(16) unsigned short Bl[128 * 64];

    const int tid  = threadIdx.x;
    const int lane = tid & 63;
    const int wid  = tid >> 6;

    int bid = blockIdx.x;                   // 1152 = 8 * 144, bijective XCD swizzle
    int lin = (bid & 7) * 144 + (bid >> 3);
    const int mt = lin % 64;
    int rest = lin / 64;                    // 0..17
    const int nt = rest % 3;
    const int kc = rest / 3;                // 0..5
    const int bm0 = mt * 128;
    const int h0  = nt * 128;
    int kb        = kc * 51;
    const int kbe = (kb + 51 < KB_TOT) ? kb + 51 : KB_TOT;

    const int l7 = lane & 7, l3 = lane >> 3;
    const int voffA = ((l7 ^ l3) << 4);
    const int rowg0 = bm0 + wid * 32 + l3;

    f32x4_t acc[4][4];
    #pragma unroll
    for (int i = 0; i < 4; ++i)
        #pragma unroll
        for (int j = 0; j < 4; ++j) acc[i][j] = (f32x4_t){0.f, 0.f, 0.f, 0.f};

    const int wr = wid >> 1, wc = wid & 1;
    const int l15 = lane & 15, l4 = lane >> 4;

    int idx4[4];
    if (kb < 300) {
        int m = kb / 100, s = kb - m * 100;
        const int* I = (m == 0) ? l_e : ((m == 1) ? m_e : t_e);
        const int* Ib = I + rowg0 * 100 + s;
        idx4[0] = Ib[0]; idx4[1] = Ib[800]; idx4[2] = Ib[1600]; idx4[3] = Ib[2400];
    }

    for (; kb < kbe; ++kb) {
        if (kb < 300) {
            #pragma unroll
            for (int p = 0; p < 4; ++p) {
                const char* src = (const char*)emb_bf + ((long)idx4[p] << 7) + voffA;
                __builtin_amdgcn_global_load_lds((GAS_u32*)src,
                    (LAS_u32*)((char*)Al + (wid * 4 + p) * 1024), 16, 0, 0);
            }
        } else {
            int q = kb - 300;
            #pragma unroll
            for (int p = 0; p < 4; ++p) {
                const char* src = (const char*)Ac_bf + (long)(rowg0 + p * 8) * 640
                                + q * 128 + voffA;
                __builtin_amdgcn_global_load_lds((GAS_u32*)src,
                    (LAS_u32*)((char*)Al + (wid * 4 + p) * 1024), 16, 0, 0);
            }
        }
        #pragma unroll
        for (int p = 0; p < 4; ++p) {
            int ch = wid * 4 + p;
            int hl = ch * 8 + l3;
            long gb = (long)(h0 + hl) * BROW + kb * 128 + ((l7 << 4) ^ (l3 << 4));
            __builtin_amdgcn_global_load_lds((GAS_u32*)((const char*)Bws + gb),
                                             (LAS_u32*)((char*)Bl + ch * 1024), 16, 0, 0);
        }
        int kn = kb + 1;
        if (kn < 300 && kn < kbe) {
            int m = kn / 100, s = kn - m * 100;
            const int* I = (m == 0) ? l_e : ((m == 1) ? m_e : t_e);
            const int* Ib = I + rowg0 * 100 + s;
            idx4[0] = Ib[0]; idx4[1] = Ib[800]; idx4[2] = Ib[1600]; idx4[3] = Ib[2400];
        }
        __syncthreads();
        #pragma unroll
        for (int ks = 0; ks < 2; ++ks) {
            int kb2 = ks * 64 + l4 * 16;
            bf16x8_t af[4], bfr[4];
            #pragma unroll
            for (int i = 0; i < 4; ++i) {
                int row = wr * 64 + i * 16 + l15;
                af[i]  = *(const bf16x8_t*)((const char*)Al + row * 128 + (kb2 ^ ((row & 7) << 4)));
                int col = wc * 64 + i * 16 + l15;
                bfr[i] = *(const bf16x8_t*)((const char*)Bl + col * 128 + (kb2 ^ ((col & 7) << 4)));
            }
            #pragma unroll
            for (int i = 0; i < 4; ++i)
                #pragma unroll
                for (int j = 0; j < 4; ++j)
                    acc[i][j] = __builtin_amdgcn_mfma_f32_16x16x32_bf16(af[i], bfr[j], acc[i][j], 0, 0, 0);
        }
        __syncthreads();
    }
    if (kc == 0) {
        #pragma unroll
        for (int i = 0; i < 4; ++i)
            #pragma unroll
            for (int j = 0; j < 4; ++j)
                #pragma unroll
                for (int r = 0; r < 4; ++r) {
                    int row = bm0 + wr * 64 + i * 16 + l4 * 4 + r;
                    int col = h0 + wc * 64 + j * 16 + l15;
                    fusion_d[row * 384 + col] = acc[i][j][r];
                }
    } else {
        unsigned short* dst = Pbf + (size_t)(kc - 1) * 3145728;
        #pragma unroll
        for (int i = 0; i < 4; ++i)
            #pragma unroll
            for (int j = 0; j < 4; ++j)
                #pragma unroll
                for (int r = 0; r < 4; ++r) {
                    int row = bm0 + wr * 64 + i * 16 + l4 * 4 + r;
                    int col = h0 + wc * 64 + j * 16 + l15;
                    dst[row * 384 + col] = f2bf(acc[i][j][r]);
                }
    }
}

// ---------- reduce split-K + b_se -> fusion_r (f32, d_out) + fusion_bf; zero e_ws ----------
__global__ __launch_bounds__(256) void reduce_fusion_kernel(float* __restrict__ fusion_d,
                                                            const unsigned short* __restrict__ Pbf,
                                                            const float* __restrict__ b_se,
                                                            unsigned short* __restrict__ fusion_bf,
                                                            float* __restrict__ e_ws) {
    if (blockIdx.x < 16) {
        int z = blockIdx.x * 1024 + threadIdx.x * 4;
        *(float4*)(e_ws + z) = make_float4(0.f, 0.f, 0.f, 0.f);
    }
    int i4 = blockIdx.x * 256 + threadIdx.x;         // grid 3072 -> 786,432 groups of 4
    int col4 = (i4 % 96) * 4;
    float4 a = *(const float4*)(fusion_d + i4 * 4);
    float4 bs = *(const float4*)(b_se + col4);
    float s0 = a.x + bs.x, s1 = a.y + bs.y, s2 = a.z + bs.z, s3 = a.w + bs.w;
    #pragma unroll
    for (int sl = 0; sl < 5; ++sl) {
        ushort4 p = *(const ushort4*)(Pbf + (size_t)sl * 3145728 + i4 * 4);
        s0 += bf2f(p.x); s1 += bf2f(p.y); s2 += bf2f(p.z); s3 += bf2f(p.w);
    }
    *(float4*)(fusion_d + i4 * 4) = make_float4(s0, s1, s2, s3);
    *(unsigned long long*)(fusion_bf + i4 * 4) = pack4bf(s0, s1, s2, s3);
}

// ---------- GAT h: hT = (fusion @ gat_W)^T, MFMA; fused e1/e2 partials ----------
__global__ __launch_bounds__(256) void gat_h_kernel(const unsigned short* __restrict__ fusion_bf,
                                                    const unsigned short* __restrict__ WT,
                                                    const float* __restrict__ gat_a,
                                                    unsigned short* __restrict__ hT,
                                                    float* __restrict__ e_ws) {
    __shared__ alignas(16) unsigned short Al[128 * 64];
    __shared__ alignas(16) unsigned short Bl[128 * 64];
    const int tid  = threadIdx.x;
    const int lane = tid & 63;
    const int wid  = tid >> 6;
    const int b  = blockIdx.x;          // 64
    const int c0 = blockIdx.y * 128;    // 3
    const int l7 = lane & 7, l3 = lane >> 3;
    const int voffA = ((l7 ^ l3) << 4);
    const int wr = wid >> 1, wc = wid & 1;
    const int l15 = lane & 15, l4 = lane >> 4;

    f32x4_t acc[4][4];
    #pragma unroll
    for (int i = 0; i < 4; ++i)
        #pragma unroll
        for (int j = 0; j < 4; ++j) acc[i][j] = (f32x4_t){0.f, 0.f, 0.f, 0.f};

    for (int kb = 0; kb < 6; ++kb) {
        #pragma unroll
        for (int p = 0; p < 4; ++p) {
            int ch = wid * 4 + p;
            int rl = ch * 8 + l3;
            long ga = (long)(b * 128 + rl) * 768 + kb * 128 + voffA;
            __builtin_amdgcn_global_load_lds((GAS_u32*)((const char*)fusion_bf + ga),
                                             (LAS_u32*)((char*)Al + ch * 1024), 16, 0, 0);
            long gb = (long)(c0 + rl) * 768 + kb * 128 + voffA;
            __builtin_amdgcn_global_load_lds((GAS_u32*)((const char*)WT + gb),
                                             (LAS_u32*)((char*)Bl + ch * 1024), 16, 0, 0);
        }
        __syncthreads();
        #pragma unroll
        for (int ks = 0; ks < 2; ++ks) {
            int kb2 = ks * 64 + l4 * 16;
            bf16x8_t af[4], bfr[4];
            #pragma unroll
            for (int i = 0; i < 4; ++i) {
                int row = wr * 64 + i * 16 + l15;
                af[i]  = *(const bf16x8_t*)((const char*)Al + row * 128 + (kb2 ^ ((row & 7) << 4)));
                int col = wc * 64 + i * 16 + l15;
                bfr[i] = *(const bf16x8_t*)((const char*)Bl + col * 128 + (kb2 ^ ((col & 7) << 4)));
            }
            #pragma unroll
            for (int i = 0; i < 4; ++i)
                #pragma unroll
                for (int j = 0; j < 4; ++j)
                    acc[i][j] = __builtin_amdgcn_mfma_f32_16x16x32_bf16(af[i], bfr[j], acc[i][j], 0, 0, 0);
        }
        __syncthreads();
    }
    // store transposed: hT[(b*384 + f)*128 + n]
    #pragma unroll
    for (int i = 0; i < 4; ++i)
        #pragma unroll
        for (int j = 0; j < 4; ++j) {
            int nb = wr * 64 + i * 16 + l4 * 4;
            int f  = c0 + wc * 64 + j * 16 + l15;
            *(unsigned long long*)(hT + ((size_t)(b * 384 + f)) * 128 + nb) =
                pack4bf(acc[i][j][0], acc[i][j][1], acc[i][j][2], acc[i][j][3]);
        }
    // fused e1/e2 partials (f32-exact): e1[n] += sum_f h(n,f)*a1(f)
    float a1v[4], a2v[4];
    #pragma unroll
    for (int j = 0; j < 4; ++j) {
        int f = c0 + wc * 64 + j * 16 + l15;
        a1v[j] = gat_a[f];
        a2v[j] = gat_a[384 + f];
    }
    #pragma unroll
    for (int i = 0; i < 4; ++i)
        #pragma unroll
        for (int r = 0; r < 4; ++r) {
            float p1 = 0.f, p2 = 0.f;
            #pragma unroll
            for (int j = 0; j < 4; ++j) {
                float hv = acc[i][j][r];
                p1 += hv * a1v[j];
                p2 += hv * a2v[j];
            }
            #pragma unroll
            for (int m = 1; m < 16; m <<= 1) {
                p1 += __shfl_xor(p1, m);
                p2 += __shfl_xor(p2, m);
            }
            if (l15 == 0) {
                int n = wr * 64 + i * 16 + l4 * 4 + r;
                atomicAdd(&e_ws[b * 128 + n], p1);
                atomicAdd(&e_ws[8192 + b * 128 + n], p2);
            }
        }
}

// ---------- GAT softmax+PV fused: x_pre_bf = relu(softmax(mask(e)) @ h) + fusion ----------
__global__ __launch_bounds__(256) void gat_pv_kernel(const float* __restrict__ e_ws,
                                                     const float* __restrict__ adj,
                                                     const unsigned short* __restrict__ hT,
                                                     const float* __restrict__ fusion_d,
                                                     unsigned short* __restrict__ x_pre_bf) {
    __shared__ alignas(16) unsigned short Pl[128 * 128];  // att, swizzled (32KB)
    __shared__ alignas(16) unsigned short Bl[128 * 128];  // hT tile, swizzled (32KB)
    __shared__ float se2[128];
    const int tid  = threadIdx.x;
    const int lane = tid & 63;
    const int wid  = tid >> 6;
    const int b  = blockIdx.x;          // 64
    const int f0 = blockIdx.y * 128;    // 3
    const int wr = wid >> 1, wc = wid & 1;
    const int l15 = lane & 15, l4 = lane >> 4;

    if (tid < 128) se2[tid] = e_ws[8192 + b * 128 + tid];
    // stage B (hT) while softmax computes: full 128x128, pre-swizzled source
    #pragma unroll
    for (int p = 0; p < 8; ++p) {
        int ch = wid * 8 + p;                  // 0..31, 1KB chunks (4 rows)
        int row = ch * 4 + (lane >> 4);
        long gb = (long)(b * 384 + f0 + row) * 256 + (((lane & 15) ^ (row & 7)) << 4);
        __builtin_amdgcn_global_load_lds((GAS_u32*)((const char*)hT + gb),
                                         (LAS_u32*)((char*)Bl + ch * 1024), 16, 0, 0);
    }
    __syncthreads();

    // softmax for row r over its half (2 threads/row), then bf16-pack into Pl swizzled
    {
        int r = tid >> 1, half = tid & 1;
        float er = e_ws[b * 128 + r];
        const float* arow = adj + r * 128 + half * 64;
        const float* e2h = se2 + half * 64;
        float mx = -1e30f;
        #pragma unroll 8
        for (int j = 0; j < 64; ++j) {
            float v = er + e2h[j];
            v = (v > 0.f) ? v : 0.2f * v;
            v = (arow[j] > 0.f) ? v : -1e12f;
            mx = fmaxf(mx, v);
        }
        mx = fmaxf(mx, __shfl_xor(mx, 1));
        float sum = 0.f;
        #pragma unroll 8
        for (int j = 0; j < 64; ++j) {
            float v = er + e2h[j];
            v = (v > 0.f) ? v : 0.2f * v;
            v = (arow[j] > 0.f) ? v : -1e12f;
            sum += __expf(v - mx);
        }
        sum += __shfl_xor(sum, 1);
        float inv = 1.f / sum;
        #pragma unroll
        for (int g = 0; g < 8; ++g) {
            float vv[8];
            #pragma unroll
            for (int q = 0; q < 8; ++q) {
                int j = g * 8 + q;
                float v = er + e2h[j];
                v = (v > 0.f) ? v : 0.2f * v;
                v = (arow[j] > 0.f) ? v : -1e12f;
                vv[q] = __expf(v - mx) * inv;
            }
            char* dst = (char*)Pl + r * 256 + ((half * 128 + g * 16) ^ ((r & 7) << 4));
            *(unsigned long long*)dst       = pack4bf(vv[0], vv[1], vv[2], vv[3]);
            *(unsigned long long*)(dst + 8) = pack4bf(vv[4], vv[5], vv[6], vv[7]);
        }
    }
    __syncthreads();

    f32x4_t acc[4][4];
    #pragma unroll
    for (int i = 0; i < 4; ++i)
        #pragma unroll
        for (int j = 0; j < 4; ++j) acc[i][j] = (f32x4_t){0.f, 0.f, 0.f, 0.f};

    #pragma unroll
    for (int st = 0; st < 4; ++st) {
        int ko = st * 64 + l4 * 16;
        bf16x8_t af[4], bfr[4];
        #pragma unroll
        for (int i = 0; i < 4; ++i) {
            int row = wr * 64 + i * 16 + l15;
            af[i]  = *(const bf16x8_t*)((const char*)Pl + row * 256 + (ko ^ ((row & 7) << 4)));
            int col = wc * 64 + i * 16 + l15;
            bfr[i] = *(const bf16x8_t*)((const char*)Bl + col * 256 + (ko ^ ((col & 7) << 4)));
        }
        #pragma unroll
        for (int i = 0; i < 4; ++i)
            #pragma unroll
            for (int j = 0; j < 4; ++j)
                acc[i][j] = __builtin_amdgcn_mfma_f32_16x16x32_bf16(af[i], bfr[j], acc[i][j], 0, 0, 0);
    }
    #pragma unroll
    for (int i = 0; i < 4; ++i)
        #pragma unroll
        for (int j = 0; j < 4; ++j) {
            int f = f0 + wc * 64 + j * 16 + l15;
            #pragma unroll
            for (int r = 0; r < 4; ++r) {
                int n = wr * 64 + i * 16 + l4 * 4 + r;
                float v = acc[i][j][r];
                v = (v > 0.f ? v : 0.f) + fusion_d[(b * 128 + n) * 384 + f];
                x_pre_bf[(size_t)b * 49152 + n * 384 + f] = f2bf(v);
            }
        }
}

// ---------- final GEMM (fp32 SIMT): partials over (n,q) ----------
__global__ __launch_bounds__(256) void final_kernel(const unsigned short* __restrict__ x_pre_bf,
                                                    const float* __restrict__ W1,
                                                    float* __restrict__ pf) {
    int n = blockIdx.x;            // 128
    int q = blockIdx.y;            // 2 -> f-range q*192..+192
    __shared__ float xl[64 * 196];
    int tid = threadIdx.x;
    #pragma unroll
    for (int p = 0; p < 6; ++p) {
        int e = p * 2048 + tid * 8;            // 12288 elems
        int b = e / 192, f = e - b * 192;
        bf16x8_t v8 = *(const bf16x8_t*)(x_pre_bf + (size_t)b * 49152 + n * 384 + q * 192 + f);
        float* d = xl + b * 196 + f;
        #pragma unroll
        for (int ii = 0; ii < 8; ++ii) d[ii] = bf2f((unsigned short)v8[ii]);
    }
    __syncthreads();
    int col = (tid & 31) * 4, bh = tid >> 5;
    float acc[8][4] = {};
    #pragma unroll 2
    for (int f = 0; f < 192; ++f) {
        float4 w = *(const float4*)(W1 + ((size_t)(n * 384 + q * 192 + f)) * 128 + col);
        #pragma unroll
        for (int bb = 0; bb < 8; ++bb) {
            float xv = xl[(bh * 8 + bb) * 196 + f];
            acc[bb][0] += xv * w.x; acc[bb][1] += xv * w.y;
            acc[bb][2] += xv * w.z; acc[bb][3] += xv * w.w;
        }
    }
    int slot = n * 2 + q;
    #pragma unroll
    for (int bb = 0; bb < 8; ++bb) {
        int b = bh * 8 + bb;
        *(float4*)(pf + (size_t)slot * 8192 + b * 128 + col) =
            make_float4(acc[bb][0], acc[bb][1], acc[bb][2], acc[bb][3]);
    }
}

// ---------- reduce final partials + b1 -> xout ----------
__global__ __launch_bounds__(256) void reduce_final_kernel(const float* __restrict__ pf,
                                                           const float* __restrict__ b1,
                                                           float* __restrict__ xout) {
    int i = blockIdx.x * 256 + threadIdx.x;   // 32 blocks -> 8192
    float acc = 0.f;
    for (int s = 0; s < 256; ++s) acc += pf[(size_t)s * 8192 + i];
    xout[i] = acc + b1[i & 127];
}

extern "C" void kernel_launch(void* const* d_in, const int* in_sizes, int n_in,
                              void* d_out, int out_size, void* d_ws, size_t ws_size,
                              hipStream_t stream) {
    (void)in_sizes; (void)n_in; (void)out_size; (void)ws_size;
    const int*   l_e   = (const int*)d_in[0];
    const int*   m_e   = (const int*)d_in[1];
    const int*   t_e   = (const int*)d_in[2];
    const float* l_c   = (const float*)d_in[3];
    const float* m_c   = (const float*)d_in[4];
    const float* t_c   = (const float*)d_in[5];
    const float* adj   = (const float*)d_in[6];
    const float* emb   = (const float*)d_in[7];
    const float* W_se  = (const float*)d_in[8];
    const float* b_se  = (const float*)d_in[9];
    const float* gat_W = (const float*)d_in[10];
    const float* gat_a = (const float*)d_in[11];
    const float* W1    = (const float*)d_in[12];
    const float* b1    = (const float*)d_in[13];

    float* xout     = (float*)d_out;
    float* fusion_d = xout + 8192;                       // output #2 (f32)

    char* ws = (char*)d_ws;
    // phase-1 regions (live through gemm)
    unsigned short* Bws    = (unsigned short*)(ws);                  // 15,728,640
    unsigned short* emb_bf = (unsigned short*)(ws + 15728640);       //    262,144
    unsigned short* Ac_bf  = (unsigned short*)(ws + 15990784);       //  5,242,880
    unsigned short* WT_bf  = (unsigned short*)(ws + 21233664);       //    294,912 (lives into gat_h)
    unsigned short* Pbf    = (unsigned short*)(ws + 21528576);       // 31,457,280 (5 bf16 slots)
    // phase-2 regions (reuse dead phase-1 space)
    unsigned short* fusion_bf = (unsigned short*)(ws);               //  6,291,456
    unsigned short* hT_bf     = (unsigned short*)(ws + 6291456);     //  6,291,456
    unsigned short* x_pre_bf  = (unsigned short*)(ws + 12582912);    //  6,291,456
    float*          e_ws      = (float*)(ws + 18874368);             //     65,536
    float*          pf        = (float*)(ws + 21528576);             //  8,388,608

    prep_kernel<<<4551, 256, 0, stream>>>(emb, l_c, m_c, t_c, W_se, gat_W,
                                          emb_bf, Ac_bf, WT_bf, Bws);
    gemm_fused_kernel<<<1152, 256, 0, stream>>>(l_e, m_e, t_e, emb_bf, Ac_bf, Bws, fusion_d, Pbf);
    reduce_fusion_kernel<<<3072, 256, 0, stream>>>(fusion_d, Pbf, b_se, fusion_bf, e_ws);
    gat_h_kernel<<<dim3(64, 3), 256, 0, stream>>>(fusion_bf, WT_bf, gat_a, hT_bf, e_ws);
    gat_pv_kernel<<<dim3(64, 3), 256, 0, stream>>>(e_ws, adj, hT_bf, fusion_d, x_pre_bf);
    final_kernel<<<dim3(128, 2), 256, 0, stream>>>(x_pre_bf, W1, pf);
    reduce_final_kernel<<<32, 256, 0, stream>>>(pf, b1, xout);
}

// Round 9
// 319.897 us; speedup vs baseline: 1.1660x; 1.1660x over previous
//
#include <hip/hip_runtime.h>

// Problem constants
#define KB_TOT 305        // 300 emb k-blocks (64 wide) + 5 c-blocks
#define KPAD   19520      // 305*64 reordered/padded K
#define BROW   39040      // bytes per B_ws row (KPAD * 2)

typedef __attribute__((ext_vector_type(8))) short bf16x8_t;
typedef __attribute__((ext_vector_type(4))) float f32x4_t;

typedef const __attribute__((address_space(1))) unsigned int GAS_u32;
typedef __attribute__((address_space(3))) unsigned int LAS_u32;

__device__ inline unsigned short f2bf(float x) {
    union { float f; unsigned u; } a; a.f = x;
    unsigned r = a.u + 0x7fffu + ((a.u >> 16) & 1u);   // RNE, finite inputs
    return (unsigned short)(r >> 16);
}
__device__ inline float bf2f(unsigned short h) {
    union { unsigned u; float f; } a; a.u = ((unsigned)h) << 16; return a.f;
}
__device__ inline unsigned long long pack4bf(float x, float y, float z, float w) {
    return (unsigned long long)f2bf(x) | ((unsigned long long)f2bf(y) << 16)
         | ((unsigned long long)f2bf(z) << 32) | ((unsigned long long)f2bf(w) << 48);
}

// ---------- merged prep: emb->bf16 | c->Ac | gat_W->WT | W_se->Bws | W1->W1T ----------
__global__ __launch_bounds__(256) void prep_kernel(
    const float* __restrict__ emb, const float* __restrict__ l_c,
    const float* __restrict__ m_c, const float* __restrict__ t_c,
    const float* __restrict__ W_se, const float* __restrict__ gat_W,
    const float* __restrict__ W1,
    unsigned short* __restrict__ ebf, unsigned short* __restrict__ Ac,
    unsigned short* __restrict__ WT, unsigned short* __restrict__ Bws,
    unsigned short* __restrict__ W1T) {
    __shared__ float tl[64 * 68];
    int bid = blockIdx.x, tid = threadIdx.x;
    if (bid < 125) {                       // emb -> bf16 (128,000 elems)
        int i4 = (bid * 256 + tid) * 4;
        float4 v = *(const float4*)(emb + i4);
        *(unsigned long long*)(ebf + i4) = pack4bf(v.x, v.y, v.z, v.w);
    } else if (bid < 2685) {               // Ac[8192][320]
        int lin = (bid - 125) * 256 + tid;
        int row = lin / 80, c4 = (lin - row * 80) * 4;
        float vv[4];
        #pragma unroll
        for (int ii = 0; ii < 4; ++ii) {
            int t = c4 + ii;
            float x = 0.f;
            if (t < 300) {
                int m = t / 100, s = t - m * 100;
                const float* C = (m == 0) ? l_c : ((m == 1) ? m_c : t_c);
                x = C[row * 100 + s] * 0.01f;
            }
            vv[ii] = x;
        }
        *(unsigned long long*)(Ac + row * 320 + c4) = pack4bf(vv[0], vv[1], vv[2], vv[3]);
    } else if (bid < 2721) {               // gat_W transpose -> WT bf16
        int idx = bid - 2685;
        int k0 = (idx % 6) * 64, n0 = (idx / 6) * 64;
        int rr = tid >> 2, c16 = (tid & 3) * 16;
        #pragma unroll
        for (int ii = 0; ii < 4; ++ii)
            *(float4*)(tl + rr * 68 + c16 + ii * 4) =
                *(const float4*)(gat_W + (k0 + rr) * 384 + n0 + c16 + ii * 4);
        __syncthreads();
        int c = tid >> 2, r16 = (tid & 3) * 16;
        unsigned long long* dst8 = (unsigned long long*)(WT + (n0 + c) * 384 + k0 + r16);
        #pragma unroll
        for (int q = 0; q < 4; ++q) {
            int rb = r16 + q * 4;
            dst8[q] = pack4bf(tl[(rb + 0) * 68 + c], tl[(rb + 1) * 68 + c],
                              tl[(rb + 2) * 68 + c], tl[(rb + 3) * 68 + c]);
        }
    } else if (bid < 4551) {               // W_se reorder+transpose -> Bws
        int idx = bid - 2721;              // 0..1829
        int kb = idx % 305, h0 = (idx / 305) * 64;
        int rr = tid >> 2, c16 = (tid & 3) * 16;
        float4 v[4];
        if (kb < 300) {
            int m = kb / 100, s = kb - m * 100;
            const float* srcp = W_se + (s * 195 + m * 65 + rr) * 384 + h0 + c16;
            #pragma unroll
            for (int ii = 0; ii < 4; ++ii) v[ii] = *(const float4*)(srcp + ii * 4);
        } else {
            int t = (kb - 300) * 64 + rr;
            if (t < 300) {
                int m = t / 100, s = t - m * 100;
                const float* srcp = W_se + (s * 195 + m * 65 + 64) * 384 + h0 + c16;
                #pragma unroll
                for (int ii = 0; ii < 4; ++ii) v[ii] = *(const float4*)(srcp + ii * 4);
            } else {
                #pragma unroll
                for (int ii = 0; ii < 4; ++ii) v[ii] = make_float4(0.f, 0.f, 0.f, 0.f);
            }
        }
        #pragma unroll
        for (int ii = 0; ii < 4; ++ii) *(float4*)(tl + rr * 68 + c16 + ii * 4) = v[ii];
        __syncthreads();
        int c = tid >> 2, r16 = (tid & 3) * 16;
        unsigned long long* dst8 =
            (unsigned long long*)(Bws + (unsigned)(h0 + c) * KPAD + kb * 64 + r16);
        #pragma unroll
        for (int q = 0; q < 4; ++q) {
            int rb = r16 + q * 4;
            dst8[q] = pack4bf(tl[(rb + 0) * 68 + c], tl[(rb + 1) * 68 + c],
                              tl[(rb + 2) * 68 + c], tl[(rb + 3) * 68 + c]);
        }
    } else {                               // W1 (49152x128) transpose -> W1T bf16 (128x49152)
        int idx = bid - 4551;              // 0..1535
        int k0 = (idx % 768) * 64, n0 = (idx / 768) * 64;
        int rr = tid >> 2, c16 = (tid & 3) * 16;
        #pragma unroll
        for (int ii = 0; ii < 4; ++ii)
            *(float4*)(tl + rr * 68 + c16 + ii * 4) =
                *(const float4*)(W1 + (size_t)(k0 + rr) * 128 + n0 + c16 + ii * 4);
        __syncthreads();
        int c = tid >> 2, r16 = (tid & 3) * 16;
        unsigned long long* dst8 =
            (unsigned long long*)(W1T + (size_t)(n0 + c) * 49152 + k0 + r16);
        #pragma unroll
        for (int q = 0; q < 4; ++q) {
            int rb = r16 + q * 4;
            dst8[q] = pack4bf(tl[(rb + 0) * 68 + c], tl[(rb + 1) * 68 + c],
                              tl[(rb + 2) * 68 + c], tl[(rb + 3) * 68 + c]);
        }
    }
}

// ---------- big GEMM: split-K x4, kc0 -> f32 fusion area, kc1..3 -> bf16 partials ----------
__global__ __launch_bounds__(256) void gemm_fused_kernel(
    const int* __restrict__ l_e, const int* __restrict__ m_e, const int* __restrict__ t_e,
    const unsigned short* __restrict__ emb_bf, const unsigned short* __restrict__ Ac_bf,
    const unsigned short* __restrict__ Bws, float* __restrict__ fusion_d,
    unsigned short* __restrict__ Pbf) {

    __shared__ alignas(16) unsigned short Al[128 * 64];
    __shared__ alignas(16) unsigned short Bl[128 * 64];

    const int tid  = threadIdx.x;
    const int lane = tid & 63;
    const int wid  = tid >> 6;

    int bid = blockIdx.x;                   // 768 = 8 * 96, bijective XCD swizzle
    int lin = (bid & 7) * 96 + (bid >> 3);
    const int mt = lin % 64;
    int rest = lin / 64;                    // 0..11
    const int nt = rest % 3;
    const int kc = rest / 3;                // 0..3
    const int bm0 = mt * 128;
    const int h0  = nt * 128;
    int kb        = (kc == 0) ? 0 : (77 + (kc - 1) * 76);
    const int kbe = 77 + kc * 76 > KB_TOT ? KB_TOT : 77 + kc * 76;

    const int l7 = lane & 7, l3 = lane >> 3;
    const int voffA = ((l7 ^ l3) << 4);
    const int rowg0 = bm0 + wid * 32 + l3;

    f32x4_t acc[4][4];
    #pragma unroll
    for (int i = 0; i < 4; ++i)
        #pragma unroll
        for (int j = 0; j < 4; ++j) acc[i][j] = (f32x4_t){0.f, 0.f, 0.f, 0.f};

    const int wr = wid >> 1, wc = wid & 1;
    const int l15 = lane & 15, l4 = lane >> 4;

    int idx4[4];
    if (kb < 300) {
        int m = kb / 100, s = kb - m * 100;
        const int* I = (m == 0) ? l_e : ((m == 1) ? m_e : t_e);
        const int* Ib = I + rowg0 * 100 + s;
        idx4[0] = Ib[0]; idx4[1] = Ib[800]; idx4[2] = Ib[1600]; idx4[3] = Ib[2400];
    }

    for (; kb < kbe; ++kb) {
        if (kb < 300) {
            #pragma unroll
            for (int p = 0; p < 4; ++p) {
                const char* src = (const char*)emb_bf + ((long)idx4[p] << 7) + voffA;
                __builtin_amdgcn_global_load_lds((GAS_u32*)src,
                    (LAS_u32*)((char*)Al + (wid * 4 + p) * 1024), 16, 0, 0);
            }
        } else {
            int q = kb - 300;
            #pragma unroll
            for (int p = 0; p < 4; ++p) {
                const char* src = (const char*)Ac_bf + (long)(rowg0 + p * 8) * 640
                                + q * 128 + voffA;
                __builtin_amdgcn_global_load_lds((GAS_u32*)src,
                    (LAS_u32*)((char*)Al + (wid * 4 + p) * 1024), 16, 0, 0);
            }
        }
        #pragma unroll
        for (int p = 0; p < 4; ++p) {
            int ch = wid * 4 + p;
            int hl = ch * 8 + l3;
            long gb = (long)(h0 + hl) * BROW + kb * 128 + ((l7 << 4) ^ (l3 << 4));
            __builtin_amdgcn_global_load_lds((GAS_u32*)((const char*)Bws + gb),
                                             (LAS_u32*)((char*)Bl + ch * 1024), 16, 0, 0);
        }
        int kn = kb + 1;
        if (kn < 300 && kn < kbe) {
            int m = kn / 100, s = kn - m * 100;
            const int* I = (m == 0) ? l_e : ((m == 1) ? m_e : t_e);
            const int* Ib = I + rowg0 * 100 + s;
            idx4[0] = Ib[0]; idx4[1] = Ib[800]; idx4[2] = Ib[1600]; idx4[3] = Ib[2400];
        }
        __syncthreads();
        #pragma unroll
        for (int ks = 0; ks < 2; ++ks) {
            int kb2 = ks * 64 + l4 * 16;
            bf16x8_t af[4], bfr[4];
            #pragma unroll
            for (int i = 0; i < 4; ++i) {
                int row = wr * 64 + i * 16 + l15;
                af[i]  = *(const bf16x8_t*)((const char*)Al + row * 128 + (kb2 ^ ((row & 7) << 4)));
                int col = wc * 64 + i * 16 + l15;
                bfr[i] = *(const bf16x8_t*)((const char*)Bl + col * 128 + (kb2 ^ ((col & 7) << 4)));
            }
            #pragma unroll
            for (int i = 0; i < 4; ++i)
                #pragma unroll
                for (int j = 0; j < 4; ++j)
                    acc[i][j] = __builtin_amdgcn_mfma_f32_16x16x32_bf16(af[i], bfr[j], acc[i][j], 0, 0, 0);
        }
        __syncthreads();
    }
    if (kc == 0) {
        #pragma unroll
        for (int i = 0; i < 4; ++i)
            #pragma unroll
            for (int j = 0; j < 4; ++j)
                #pragma unroll
                for (int r = 0; r < 4; ++r) {
                    int row = bm0 + wr * 64 + i * 16 + l4 * 4 + r;
                    int col = h0 + wc * 64 + j * 16 + l15;
                    fusion_d[row * 384 + col] = acc[i][j][r];
                }
    } else {
        unsigned short* dst = Pbf + (size_t)(kc - 1) * 3145728;
        #pragma unroll
        for (int i = 0; i < 4; ++i)
            #pragma unroll
            for (int j = 0; j < 4; ++j)
                #pragma unroll
                for (int r = 0; r < 4; ++r) {
                    int row = bm0 + wr * 64 + i * 16 + l4 * 4 + r;
                    int col = h0 + wc * 64 + j * 16 + l15;
                    dst[row * 384 + col] = f2bf(acc[i][j][r]);
                }
    }
}

// ---------- reduce split-K + b_se -> fusion_r (f32, d_out) + fusion_bf; zero e_ws ----------
__global__ __launch_bounds__(256) void reduce_fusion_kernel(float* __restrict__ fusion_d,
                                                            const unsigned short* __restrict__ Pbf,
                                                            const float* __restrict__ b_se,
                                                            unsigned short* __restrict__ fusion_bf,
                                                            float* __restrict__ e_ws) {
    if (blockIdx.x < 16) {
        int z = blockIdx.x * 1024 + threadIdx.x * 4;
        *(float4*)(e_ws + z) = make_float4(0.f, 0.f, 0.f, 0.f);
    }
    int i4 = blockIdx.x * 256 + threadIdx.x;         // grid 3072 -> 786,432 groups of 4
    int col4 = (i4 % 96) * 4;
    float4 a = *(const float4*)(fusion_d + i4 * 4);
    float4 bs = *(const float4*)(b_se + col4);
    float s0 = a.x + bs.x, s1 = a.y + bs.y, s2 = a.z + bs.z, s3 = a.w + bs.w;
    #pragma unroll
    for (int sl = 0; sl < 3; ++sl) {
        ushort4 p = *(const ushort4*)(Pbf + (size_t)sl * 3145728 + i4 * 4);
        s0 += bf2f(p.x); s1 += bf2f(p.y); s2 += bf2f(p.z); s3 += bf2f(p.w);
    }
    *(float4*)(fusion_d + i4 * 4) = make_float4(s0, s1, s2, s3);
    *(unsigned long long*)(fusion_bf + i4 * 4) = pack4bf(s0, s1, s2, s3);
}

// ---------- GAT h: hT = (fusion @ gat_W)^T, MFMA; fused e1/e2 partials ----------
__global__ __launch_bounds__(256) void gat_h_kernel(const unsigned short* __restrict__ fusion_bf,
                                                    const unsigned short* __restrict__ WT,
                                                    const float* __restrict__ gat_a,
                                                    unsigned short* __restrict__ hT,
                                                    float* __restrict__ e_ws) {
    __shared__ alignas(16) unsigned short Al[128 * 64];
    __shared__ alignas(16) unsigned short Bl[128 * 64];
    const int tid  = threadIdx.x;
    const int lane = tid & 63;
    const int wid  = tid >> 6;
    const int b  = blockIdx.x;          // 64
    const int c0 = blockIdx.y * 128;    // 3
    const int l7 = lane & 7, l3 = lane >> 3;
    const int voffA = ((l7 ^ l3) << 4);
    const int wr = wid >> 1, wc = wid & 1;
    const int l15 = lane & 15, l4 = lane >> 4;

    f32x4_t acc[4][4];
    #pragma unroll
    for (int i = 0; i < 4; ++i)
        #pragma unroll
        for (int j = 0; j < 4; ++j) acc[i][j] = (f32x4_t){0.f, 0.f, 0.f, 0.f};

    for (int kb = 0; kb < 6; ++kb) {
        #pragma unroll
        for (int p = 0; p < 4; ++p) {
            int ch = wid * 4 + p;
            int rl = ch * 8 + l3;
            long ga = (long)(b * 128 + rl) * 768 + kb * 128 + voffA;
            __builtin_amdgcn_global_load_lds((GAS_u32*)((const char*)fusion_bf + ga),
                                             (LAS_u32*)((char*)Al + ch * 1024), 16, 0, 0);
            long gb = (long)(c0 + rl) * 768 + kb * 128 + voffA;
            __builtin_amdgcn_global_load_lds((GAS_u32*)((const char*)WT + gb),
                                             (LAS_u32*)((char*)Bl + ch * 1024), 16, 0, 0);
        }
        __syncthreads();
        #pragma unroll
        for (int ks = 0; ks < 2; ++ks) {
            int kb2 = ks * 64 + l4 * 16;
            bf16x8_t af[4], bfr[4];
            #pragma unroll
            for (int i = 0; i < 4; ++i) {
                int row = wr * 64 + i * 16 + l15;
                af[i]  = *(const bf16x8_t*)((const char*)Al + row * 128 + (kb2 ^ ((row & 7) << 4)));
                int col = wc * 64 + i * 16 + l15;
                bfr[i] = *(const bf16x8_t*)((const char*)Bl + col * 128 + (kb2 ^ ((col & 7) << 4)));
            }
            #pragma unroll
            for (int i = 0; i < 4; ++i)
                #pragma unroll
                for (int j = 0; j < 4; ++j)
                    acc[i][j] = __builtin_amdgcn_mfma_f32_16x16x32_bf16(af[i], bfr[j], acc[i][j], 0, 0, 0);
        }
        __syncthreads();
    }
    // store transposed: hT[(b*384 + f)*128 + n]
    #pragma unroll
    for (int i = 0; i < 4; ++i)
        #pragma unroll
        for (int j = 0; j < 4; ++j) {
            int nb = wr * 64 + i * 16 + l4 * 4;
            int f  = c0 + wc * 64 + j * 16 + l15;
            *(unsigned long long*)(hT + ((size_t)(b * 384 + f)) * 128 + nb) =
                pack4bf(acc[i][j][0], acc[i][j][1], acc[i][j][2], acc[i][j][3]);
        }
    // fused e1/e2 partials (f32-exact): e1[n] += sum_f h(n,f)*a1(f)
    float a1v[4], a2v[4];
    #pragma unroll
    for (int j = 0; j < 4; ++j) {
        int f = c0 + wc * 64 + j * 16 + l15;
        a1v[j] = gat_a[f];
        a2v[j] = gat_a[384 + f];
    }
    #pragma unroll
    for (int i = 0; i < 4; ++i)
        #pragma unroll
        for (int r = 0; r < 4; ++r) {
            float p1 = 0.f, p2 = 0.f;
            #pragma unroll
            for (int j = 0; j < 4; ++j) {
                float hv = acc[i][j][r];
                p1 += hv * a1v[j];
                p2 += hv * a2v[j];
            }
            #pragma unroll
            for (int m = 1; m < 16; m <<= 1) {
                p1 += __shfl_xor(p1, m);
                p2 += __shfl_xor(p2, m);
            }
            if (l15 == 0) {
                int n = wr * 64 + i * 16 + l4 * 4 + r;
                atomicAdd(&e_ws[b * 128 + n], p1);
                atomicAdd(&e_ws[8192 + b * 128 + n], p2);
            }
        }
}

// ---------- GAT softmax+PV fused: x_pre_bf = relu(softmax(mask(e)) @ h) + fusion ----------
__global__ __launch_bounds__(256) void gat_pv_kernel(const float* __restrict__ e_ws,
                                                     const float* __restrict__ adj,
                                                     const unsigned short* __restrict__ hT,
                                                     const float* __restrict__ fusion_d,
                                                     unsigned short* __restrict__ x_pre_bf) {
    __shared__ alignas(16) unsigned short Pl[128 * 128];  // att, swizzled (32KB)
    __shared__ alignas(16) unsigned short Bl[128 * 128];  // hT tile, swizzled (32KB)
    __shared__ float se2[128];
    const int tid  = threadIdx.x;
    const int lane = tid & 63;
    const int wid  = tid >> 6;
    const int b  = blockIdx.x;          // 64
    const int f0 = blockIdx.y * 128;    // 3
    const int wr = wid >> 1, wc = wid & 1;
    const int l15 = lane & 15, l4 = lane >> 4;

    if (tid < 128) se2[tid] = e_ws[8192 + b * 128 + tid];
    // stage B (hT) while softmax computes: full 128x128, pre-swizzled source
    #pragma unroll
    for (int p = 0; p < 8; ++p) {
        int ch = wid * 8 + p;                  // 0..31, 1KB chunks (4 rows)
        int row = ch * 4 + (lane >> 4);
        long gb = (long)(b * 384 + f0 + row) * 256 + (((lane & 15) ^ (row & 7)) << 4);
        __builtin_amdgcn_global_load_lds((GAS_u32*)((const char*)hT + gb),
                                         (LAS_u32*)((char*)Bl + ch * 1024), 16, 0, 0);
    }
    __syncthreads();

    // softmax for row r over its half (2 threads/row), then bf16-pack into Pl swizzled
    {
        int r = tid >> 1, half = tid & 1;
        float er = e_ws[b * 128 + r];
        const float* arow = adj + r * 128 + half * 64;
        const float* e2h = se2 + half * 64;
        float mx = -1e30f;
        #pragma unroll 8
        for (int j = 0; j < 64; ++j) {
            float v = er + e2h[j];
            v = (v > 0.f) ? v : 0.2f * v;
            v = (arow[j] > 0.f) ? v : -1e12f;
            mx = fmaxf(mx, v);
        }
        mx = fmaxf(mx, __shfl_xor(mx, 1));
        float sum = 0.f;
        #pragma unroll 8
        for (int j = 0; j < 64; ++j) {
            float v = er + e2h[j];
            v = (v > 0.f) ? v : 0.2f * v;
            v = (arow[j] > 0.f) ? v : -1e12f;
            sum += __expf(v - mx);
        }
        sum += __shfl_xor(sum, 1);
        float inv = 1.f / sum;
        #pragma unroll
        for (int g = 0; g < 8; ++g) {
            float vv[8];
            #pragma unroll
            for (int q = 0; q < 8; ++q) {
                int j = g * 8 + q;
                float v = er + e2h[j];
                v = (v > 0.f) ? v : 0.2f * v;
                v = (arow[j] > 0.f) ? v : -1e12f;
                vv[q] = __expf(v - mx) * inv;
            }
            char* dst = (char*)Pl + r * 256 + ((half * 128 + g * 16) ^ ((r & 7) << 4));
            *(unsigned long long*)dst       = pack4bf(vv[0], vv[1], vv[2], vv[3]);
            *(unsigned long long*)(dst + 8) = pack4bf(vv[4], vv[5], vv[6], vv[7]);
        }
    }
    __syncthreads();

    f32x4_t acc[4][4];
    #pragma unroll
    for (int i = 0; i < 4; ++i)
        #pragma unroll
        for (int j = 0; j < 4; ++j) acc[i][j] = (f32x4_t){0.f, 0.f, 0.f, 0.f};

    #pragma unroll
    for (int st = 0; st < 4; ++st) {
        int ko = st * 64 + l4 * 16;
        bf16x8_t af[4], bfr[4];
        #pragma unroll
        for (int i = 0; i < 4; ++i) {
            int row = wr * 64 + i * 16 + l15;
            af[i]  = *(const bf16x8_t*)((const char*)Pl + row * 256 + (ko ^ ((row & 7) << 4)));
            int col = wc * 64 + i * 16 + l15;
            bfr[i] = *(const bf16x8_t*)((const char*)Bl + col * 256 + (ko ^ ((col & 7) << 4)));
        }
        #pragma unroll
        for (int i = 0; i < 4; ++i)
            #pragma unroll
            for (int j = 0; j < 4; ++j)
                acc[i][j] = __builtin_amdgcn_mfma_f32_16x16x32_bf16(af[i], bfr[j], acc[i][j], 0, 0, 0);
    }
    #pragma unroll
    for (int i = 0; i < 4; ++i)
        #pragma unroll
        for (int j = 0; j < 4; ++j) {
            int f = f0 + wc * 64 + j * 16 + l15;
            #pragma unroll
            for (int r = 0; r < 4; ++r) {
                int n = wr * 64 + i * 16 + l4 * 4 + r;
                float v = acc[i][j][r];
                v = (v > 0.f ? v : 0.f) + fusion_d[(b * 128 + n) * 384 + f];
                x_pre_bf[(size_t)b * 49152 + n * 384 + f] = f2bf(v);
            }
        }
}

// ---------- final GEMM (MFMA): xout_pre[64][128] split-K over 256 blocks ----------
__global__ __launch_bounds__(256) void final_kernel(const unsigned short* __restrict__ x_pre_bf,
                                                    const unsigned short* __restrict__ W1T,
                                                    float* __restrict__ pf) {
    __shared__ alignas(16) unsigned short Al[64 * 64];    // A: 64 b-rows x 64 k (8KB)
    __shared__ alignas(16) unsigned short Bl[128 * 64];   // B: 128 cols x 64 k (16KB)
    const int tid  = threadIdx.x;
    const int lane = tid & 63;
    const int wid  = tid >> 6;
    const int kc   = blockIdx.x;        // 256 slices of K=192
    const int l7 = lane & 7, l3 = lane >> 3;
    const int voffA = ((l7 ^ l3) << 4);
    const int l15 = lane & 15, l4 = lane >> 4;

    f32x4_t acc[4][2];
    #pragma unroll
    for (int i = 0; i < 4; ++i) {
        acc[i][0] = (f32x4_t){0.f, 0.f, 0.f, 0.f};
        acc[i][1] = (f32x4_t){0.f, 0.f, 0.f, 0.f};
    }

    for (int ks = 0; ks < 3; ++ks) {
        // A: 8 chunks of 1KB (8 rows), 2 per wave
        #pragma unroll
        for (int p = 0; p < 2; ++p) {
            int ch = wid * 2 + p;
            int row = ch * 8 + l3;
            long ga = (long)row * 98304 + kc * 384 + ks * 128 + voffA;
            __builtin_amdgcn_global_load_lds((GAS_u32*)((const char*)x_pre_bf + ga),
                                             (LAS_u32*)((char*)Al + ch * 1024), 16, 0, 0);
        }
        // B: 16 chunks of 1KB (8 cols), 4 per wave
        #pragma unroll
        for (int p = 0; p < 4; ++p) {
            int ch = wid * 4 + p;
            int col = ch * 8 + l3;
            long gb = (long)col * 98304 + kc * 384 + ks * 128 + voffA;
            __builtin_amdgcn_global_load_lds((GAS_u32*)((const char*)W1T + gb),
                                             (LAS_u32*)((char*)Bl + ch * 1024), 16, 0, 0);
        }
        __syncthreads();
        #pragma unroll
        for (int ks2 = 0; ks2 < 2; ++ks2) {
            int kb2 = ks2 * 64 + l4 * 16;
            bf16x8_t af[4], bfr[2];
            #pragma unroll
            for (int i = 0; i < 4; ++i) {
                int row = i * 16 + l15;
                af[i] = *(const bf16x8_t*)((const char*)Al + row * 128 + (kb2 ^ ((row & 7) << 4)));
            }
            #pragma unroll
            for (int j = 0; j < 2; ++j) {
                int col = wid * 32 + j * 16 + l15;
                bfr[j] = *(const bf16x8_t*)((const char*)Bl + col * 128 + (kb2 ^ ((col & 7) << 4)));
            }
            #pragma unroll
            for (int i = 0; i < 4; ++i) {
                acc[i][0] = __builtin_amdgcn_mfma_f32_16x16x32_bf16(af[i], bfr[0], acc[i][0], 0, 0, 0);
                acc[i][1] = __builtin_amdgcn_mfma_f32_16x16x32_bf16(af[i], bfr[1], acc[i][1], 0, 0, 0);
            }
        }
        __syncthreads();
    }
    float* dst = pf + (size_t)kc * 8192;
    #pragma unroll
    for (int i = 0; i < 4; ++i)
        #pragma unroll
        for (int j = 0; j < 2; ++j) {
            int col = wid * 32 + j * 16 + l15;
            #pragma unroll
            for (int r = 0; r < 4; ++r) {
                int row = i * 16 + l4 * 4 + r;
                dst[row * 128 + col] = acc[i][j][r];
            }
        }
}

// ---------- reduce final partials + b1 -> xout ----------
__global__ __launch_bounds__(256) void reduce_final_kernel(const float* __restrict__ pf,
                                                           const float* __restrict__ b1,
                                                           float* __restrict__ xout) {
    int i = blockIdx.x * 256 + threadIdx.x;   // 32 blocks -> 8192
    float acc = 0.f;
    #pragma unroll 8
    for (int s = 0; s < 256; ++s) acc += pf[(size_t)s * 8192 + i];
    xout[i] = acc + b1[i & 127];
}

extern "C" void kernel_launch(void* const* d_in, const int* in_sizes, int n_in,
                              void* d_out, int out_size, void* d_ws, size_t ws_size,
                              hipStream_t stream) {
    (void)in_sizes; (void)n_in; (void)out_size; (void)ws_size;
    const int*   l_e   = (const int*)d_in[0];
    const int*   m_e   = (const int*)d_in[1];
    const int*   t_e   = (const int*)d_in[2];
    const float* l_c   = (const float*)d_in[3];
    const float* m_c   = (const float*)d_in[4];
    const float* t_c   = (const float*)d_in[5];
    const float* adj   = (const float*)d_in[6];
    const float* emb   = (const float*)d_in[7];
    const float* W_se  = (const float*)d_in[8];
    const float* b_se  = (const float*)d_in[9];
    const float* gat_W = (const float*)d_in[10];
    const float* gat_a = (const float*)d_in[11];
    const float* W1    = (const float*)d_in[12];
    const float* b1    = (const float*)d_in[13];

    float* xout     = (float*)d_out;
    float* fusion_d = xout + 8192;                       // output #2 (f32)

    char* ws = (char*)d_ws;
    // phase-1 regions (live through gemm)
    unsigned short* Bws    = (unsigned short*)(ws);                  // 15,728,640
    unsigned short* emb_bf = (unsigned short*)(ws + 15728640);       //    262,144
    unsigned short* Ac_bf  = (unsigned short*)(ws + 15990784);       //  5,242,880
    unsigned short* WT_bf  = (unsigned short*)(ws + 21233664);       //    294,912 (lives into gat_h)
    unsigned short* Pbf    = (unsigned short*)(ws + 21528576);       // 18,874,368 (3 bf16 slots)
    unsigned short* W1T_bf = (unsigned short*)(ws + 40402944);       // 12,582,912 (lives to final)
    // phase-2 regions (reuse dead phase-1 space)
    unsigned short* fusion_bf = (unsigned short*)(ws);               //  6,291,456
    unsigned short* hT_bf     = (unsigned short*)(ws + 6291456);     //  6,291,456
    unsigned short* x_pre_bf  = (unsigned short*)(ws + 12582912);    //  6,291,456
    float*          e_ws      = (float*)(ws + 18874368);             //     65,536
    float*          pf        = (float*)(ws + 21528576);             //  8,388,608 (overlays dead Pbf)

    prep_kernel<<<6087, 256, 0, stream>>>(emb, l_c, m_c, t_c, W_se, gat_W, W1,
                                          emb_bf, Ac_bf, WT_bf, Bws, W1T_bf);
    gemm_fused_kernel<<<768, 256, 0, stream>>>(l_e, m_e, t_e, emb_bf, Ac_bf, Bws, fusion_d, Pbf);
    reduce_fusion_kernel<<<3072, 256, 0, stream>>>(fusion_d, Pbf, b_se, fusion_bf, e_ws);
    gat_h_kernel<<<dim3(64, 3), 256, 0, stream>>>(fusion_bf, WT_bf, gat_a, hT_bf, e_ws);
    gat_pv_kernel<<<dim3(64, 3), 256, 0, stream>>>(e_ws, adj, hT_bf, fusion_d, x_pre_bf);
    final_kernel<<<256, 256, 0, stream>>>(x_pre_bf, W1T_bf, pf);
    reduce_final_kernel<<<32, 256, 0, stream>>>(pf, b1, xout);
}